// Round 1
// baseline (27.320 us; speedup 1.0000x reference)
//
#include <hip/hip_runtime.h>
#include <math.h>

#define NW 4
#define NL 3

// One block per image (256 threads).
// Phase 1: threads 0..15 each simulate one basis-state column of the fixed
//          3-layer entangling circuit -> U (16x16 complex) in LDS.
// Phase 2: all threads compute A[w][i][j] = Re(U^dag Z_w U)[i][j] in LDS.
// Phase 3: thread t (t<196) handles patch t: v = tensor-prod of RY 2-vectors,
//          q_w = v^T A_w v, partial logits via W, then block reduction +
//          log_softmax.
__global__ __launch_bounds__(256) void quanv_fused_kernel(
    const float* __restrict__ x,       // [B,784]  (28x28)
    const float* __restrict__ params,  // [3,4,3]
    const float* __restrict__ Wm,      // [10,784]
    const float* __restrict__ bv,      // [10]
    float* __restrict__ out)           // [B,10]
{
    __shared__ float Ur[16][17];
    __shared__ float Ui[16][17];
    __shared__ float Amat[4][16][16];
    __shared__ float red[4][10];

    const int tid = threadIdx.x;
    const int b   = blockIdx.x;

    // ---------------- Phase 1: build U columns ----------------
    if (tid < 16) {
        const int col = tid;
        float sr[16], si[16];
#pragma unroll
        for (int k = 0; k < 16; ++k) { sr[k] = (k == col) ? 1.f : 0.f; si[k] = 0.f; }

#pragma unroll
        for (int l = 0; l < NL; ++l) {
            // Rot on each wire
#pragma unroll
            for (int w = 0; w < NW; ++w) {
                const float phi = params[(l * 4 + w) * 3 + 0];
                const float th  = params[(l * 4 + w) * 3 + 1];
                const float om  = params[(l * 4 + w) * 3 + 2];
                float sa, ca, sb, cb, st, ct;
                sincosf(0.5f * (phi + om), &sa, &ca);
                sincosf(0.5f * (phi - om), &sb, &cb);
                sincosf(0.5f * th, &st, &ct);
                // m00 = ct*e^{-i a}; m01 = -st*e^{+i b}; m10 = st*e^{-i b}; m11 = ct*e^{+i a}
                const float m00r =  ct * ca, m00i = -ct * sa;
                const float m01r = -st * cb, m01i = -st * sb;
                const float m10r =  st * cb, m10i = -st * sb;
                const float m11r =  ct * ca, m11i =  ct * sa;
                const int m = 8 >> w;  // wire 0 = MSB
#pragma unroll
                for (int i = 0; i < 16; ++i) {
                    if (!(i & m)) {
                        const int i1 = i | m;
                        const float a0r = sr[i],  a0i = si[i];
                        const float a1r = sr[i1], a1i = si[i1];
                        sr[i]  = m00r * a0r - m00i * a0i + m01r * a1r - m01i * a1i;
                        si[i]  = m00r * a0i + m00i * a0r + m01r * a1i + m01i * a1r;
                        sr[i1] = m10r * a0r - m10i * a0i + m11r * a1r - m11i * a1i;
                        si[i1] = m10r * a0i + m10i * a0r + m11r * a1i + m11i * a1r;
                    }
                }
            }
            // CNOT ring with range r = l % 3 + 1, control w -> target (w+r)%4
            const int r = (l % 3) + 1;
#pragma unroll
            for (int w = 0; w < NW; ++w) {
                const int c  = w;
                const int t  = (w + r) & 3;
                const int cm = 8 >> c;
                const int tm = 8 >> t;
#pragma unroll
                for (int i = 0; i < 16; ++i) {
                    if ((i & cm) && !(i & tm)) {
                        const int i1 = i | tm;
                        const float tr = sr[i], ti = si[i];
                        sr[i]  = sr[i1]; si[i]  = si[i1];
                        sr[i1] = tr;     si[i1] = ti;
                    }
                }
            }
        }
#pragma unroll
        for (int k = 0; k < 16; ++k) { Ur[k][col] = sr[k]; Ui[k][col] = si[k]; }
    }
    __syncthreads();

    // ---------------- Phase 2: A[w][i][j] = sum_k sign_w(k) * Re(conj(U[k][i]) U[k][j]) ----------------
    for (int e = tid; e < 1024; e += 256) {
        const int w = e >> 8, i = (e >> 4) & 15, j = e & 15;
        float s = 0.f;
#pragma unroll
        for (int k = 0; k < 16; ++k) {
            const float sign = ((k >> (3 - w)) & 1) ? -1.f : 1.f;
            s += sign * (Ur[k][i] * Ur[k][j] + Ui[k][i] * Ui[k][j]);
        }
        Amat[w][i][j] = s;
    }
    __syncthreads();

    // ---------------- Phase 3: per-patch quadratic forms + W projection ----------------
    float lg[10];
#pragma unroll
    for (int o = 0; o < 10; ++o) lg[o] = 0.f;

    if (tid < 196) {
        const int pi = tid / 14, pj = tid % 14;
        const float* xb = x + b * 784 + pi * 56 + pj * 2;
        const float a0 = xb[0], a1 = xb[1], a2 = xb[28], a3 = xb[29];
        float c0, s0, c1, s1, c2, s2, c3, s3;
        sincosf(0.5f * a0, &s0, &c0);
        sincosf(0.5f * a1, &s1, &c1);
        sincosf(0.5f * a2, &s2, &c2);
        sincosf(0.5f * a3, &s3, &c3);

        // v[idx], idx bits (q0 q1 q2 q3), wire0 = MSB
        float tt[4], uu[4];
        tt[0] = c0 * c1; tt[1] = c0 * s1; tt[2] = s0 * c1; tt[3] = s0 * s1;
        uu[0] = c2 * c3; uu[1] = c2 * s3; uu[2] = s2 * c3; uu[3] = s2 * s3;
        float v[16];
#pragma unroll
        for (int idx = 0; idx < 16; ++idx) v[idx] = tt[idx >> 2] * uu[idx & 3];

        float q[4];
#pragma unroll
        for (int w = 0; w < 4; ++w) {
            float acc = 0.f;
#pragma unroll
            for (int i = 0; i < 16; ++i) {
                float u = 0.f;
#pragma unroll
                for (int j0 = 0; j0 < 16; j0 += 4) {
                    const float4 a = *(const float4*)&Amat[w][i][j0];
                    u = fmaf(a.x, v[j0 + 0], u);
                    u = fmaf(a.y, v[j0 + 1], u);
                    u = fmaf(a.z, v[j0 + 2], u);
                    u = fmaf(a.w, v[j0 + 3], u);
                }
                acc = fmaf(u, v[i], acc);
            }
            q[w] = acc;
        }

        // partial logits: W[o, tid*4 + w] -> float4 index o*196 + tid
        const float4* Wp = (const float4*)Wm;
#pragma unroll
        for (int o = 0; o < 10; ++o) {
            const float4 wv = Wp[o * 196 + tid];
            lg[o] = fmaf(q[0], wv.x, fmaf(q[1], wv.y, fmaf(q[2], wv.z, fmaf(q[3], wv.w, lg[o]))));
        }
    }

    // ---------------- Reduction over 256 threads ----------------
#pragma unroll
    for (int off = 32; off; off >>= 1) {
#pragma unroll
        for (int o = 0; o < 10; ++o) lg[o] += __shfl_down(lg[o], off, 64);
    }
    const int lane = tid & 63, wid = tid >> 6;
    if (lane == 0) {
#pragma unroll
        for (int o = 0; o < 10; ++o) red[wid][o] = lg[o];
    }
    __syncthreads();
    if (tid == 0) {
        float logits[10];
        float mx = -1e30f;
#pragma unroll
        for (int o = 0; o < 10; ++o) {
            logits[o] = red[0][o] + red[1][o] + red[2][o] + red[3][o] + bv[o];
            mx = fmaxf(mx, logits[o]);
        }
        float se = 0.f;
#pragma unroll
        for (int o = 0; o < 10; ++o) se += expf(logits[o] - mx);
        const float lse = mx + logf(se);
#pragma unroll
        for (int o = 0; o < 10; ++o) out[b * 10 + o] = logits[o] - lse;
    }
}

extern "C" void kernel_launch(void* const* d_in, const int* in_sizes, int n_in,
                              void* d_out, int out_size, void* d_ws, size_t ws_size,
                              hipStream_t stream) {
    const float* x      = (const float*)d_in[0];  // [B,1,28,28]
    const float* params = (const float*)d_in[1];  // [3,4,3]
    const float* Wm     = (const float*)d_in[2];  // [10,784]
    const float* bv     = (const float*)d_in[3];  // [10]
    float* out          = (float*)d_out;          // [B,10]

    const int B = in_sizes[0] / 784;
    quanv_fused_kernel<<<B, 256, 0, stream>>>(x, params, Wm, bv, out);
}

// Round 2
// 26.911 us; speedup vs baseline: 1.0152x; 1.0152x over previous
//
#include <hip/hip_runtime.h>
#include <math.h>

#define NW 4
#define NL 3

// ---------------------------------------------------------------------------
// Kernel A (one block, runs once): build the fixed 16x16 circuit unitary U,
// then pack A_w = Re(U^dag Z_w U) as symmetric-packed A2[pair][w] (float4 per
// pair, factor 2 folded into off-diagonal entries) into d_ws.
// ---------------------------------------------------------------------------
__global__ __launch_bounds__(256) void quanv_prep_kernel(
    const float* __restrict__ params,  // [3,4,3]
    float* __restrict__ A2)            // [136,4]
{
    __shared__ float Ur[16][17];
    __shared__ float Ui[16][17];
    __shared__ float Amat[4][16][16];

    const int tid = threadIdx.x;

    if (tid < 16) {
        const int col = tid;
        float sr[16], si[16];
#pragma unroll
        for (int k = 0; k < 16; ++k) { sr[k] = (k == col) ? 1.f : 0.f; si[k] = 0.f; }

#pragma unroll
        for (int l = 0; l < NL; ++l) {
#pragma unroll
            for (int w = 0; w < NW; ++w) {
                const float phi = params[(l * 4 + w) * 3 + 0];
                const float th  = params[(l * 4 + w) * 3 + 1];
                const float om  = params[(l * 4 + w) * 3 + 2];
                float sa, ca, sb, cb, st, ct;
                sincosf(0.5f * (phi + om), &sa, &ca);
                sincosf(0.5f * (phi - om), &sb, &cb);
                sincosf(0.5f * th, &st, &ct);
                const float m00r =  ct * ca, m00i = -ct * sa;
                const float m01r = -st * cb, m01i = -st * sb;
                const float m10r =  st * cb, m10i = -st * sb;
                const float m11r =  ct * ca, m11i =  ct * sa;
                const int m = 8 >> w;  // wire 0 = MSB
#pragma unroll
                for (int i = 0; i < 16; ++i) {
                    if (!(i & m)) {
                        const int i1 = i | m;
                        const float a0r = sr[i],  a0i = si[i];
                        const float a1r = sr[i1], a1i = si[i1];
                        sr[i]  = m00r * a0r - m00i * a0i + m01r * a1r - m01i * a1i;
                        si[i]  = m00r * a0i + m00i * a0r + m01r * a1i + m01i * a1r;
                        sr[i1] = m10r * a0r - m10i * a0i + m11r * a1r - m11i * a1i;
                        si[i1] = m10r * a0i + m10i * a0r + m11r * a1i + m11i * a1r;
                    }
                }
            }
            const int r = (l % 3) + 1;
#pragma unroll
            for (int w = 0; w < NW; ++w) {
                const int cm = 8 >> w;
                const int tm = 8 >> ((w + r) & 3);
#pragma unroll
                for (int i = 0; i < 16; ++i) {
                    if ((i & cm) && !(i & tm)) {
                        const int i1 = i | tm;
                        const float tr = sr[i], ti = si[i];
                        sr[i]  = sr[i1]; si[i]  = si[i1];
                        sr[i1] = tr;     si[i1] = ti;
                    }
                }
            }
        }
#pragma unroll
        for (int k = 0; k < 16; ++k) { Ur[k][col] = sr[k]; Ui[k][col] = si[k]; }
    }
    __syncthreads();

    // A[w][i][j] = sum_k sign_w(k) * Re(conj(U[k][i]) U[k][j])
    for (int e = tid; e < 1024; e += 256) {
        const int w = e >> 8, i = (e >> 4) & 15, j = e & 15;
        float s = 0.f;
#pragma unroll
        for (int k = 0; k < 16; ++k) {
            const float sign = ((k >> (3 - w)) & 1) ? -1.f : 1.f;
            s += sign * (Ur[k][i] * Ur[k][j] + Ui[k][i] * Ui[k][j]);
        }
        Amat[w][i][j] = s;
    }
    __syncthreads();

    // pack upper triangle: pair p = (i,j) i<=j row-major; off-diag gets 2x
    for (int e = tid; e < 544; e += 256) {
        const int p = e >> 2, w = e & 3;
        int i = 0, rem = p;
        while (rem >= 16 - i) { rem -= 16 - i; ++i; }
        const int j = i + rem;
        A2[p * 4 + w] = Amat[w][i][j] * ((i == j) ? 1.f : 2.f);
    }
}

// ---------------------------------------------------------------------------
// Kernel B: one block per image. Each thread owns one patch; A2 is read with
// wave-uniform addresses (scalar loads). No divergence: lanes >=196 compute a
// clamped duplicate patch and are masked out of the reduction.
// ---------------------------------------------------------------------------
__global__ __launch_bounds__(256) void quanv_main_kernel(
    const float* __restrict__ x,       // [B,784]
    const float* __restrict__ A2g,     // [136,4]
    const float* __restrict__ Wm,      // [10,784]
    const float* __restrict__ bv,      // [10]
    float* __restrict__ out)           // [B,10]
{
    __shared__ float red[4][10];

    const int tid = threadIdx.x;
    const int b   = blockIdx.x;
    const float mask = (tid < 196) ? 1.f : 0.f;
    const int pidx = (tid < 196) ? tid : 195;

    const int pi = pidx / 14, pj = pidx % 14;
    const float* xb = x + b * 784 + pi * 56 + pj * 2;
    const float a0 = xb[0], a1 = xb[1], a2 = xb[28], a3 = xb[29];
    float c0, s0, c1, s1, c2, s2, c3, s3;
    sincosf(0.5f * a0, &s0, &c0);
    sincosf(0.5f * a1, &s1, &c1);
    sincosf(0.5f * a2, &s2, &c2);
    sincosf(0.5f * a3, &s3, &c3);

    float tt[4], uu[4];
    tt[0] = c0 * c1; tt[1] = c0 * s1; tt[2] = s0 * c1; tt[3] = s0 * s1;
    uu[0] = c2 * c3; uu[1] = c2 * s3; uu[2] = s2 * c3; uu[3] = s2 * s3;
    float v[16];
#pragma unroll
    for (int idx = 0; idx < 16; ++idx) v[idx] = tt[idx >> 2] * uu[idx & 3];

    // q_w = sum_{i<=j} A2[p][w] * v_i * v_j   (A2 loads are wave-uniform)
    const float4* __restrict__ A2v = (const float4*)A2g;
    float qx = 0.f, qy = 0.f, qz = 0.f, qw = 0.f;
    {
        int p = 0;
#pragma unroll
        for (int i = 0; i < 16; ++i) {
#pragma unroll
            for (int j = i; j < 16; ++j) {
                const float prod = v[i] * v[j];
                const float4 a = A2v[p];
                qx = fmaf(a.x, prod, qx);
                qy = fmaf(a.y, prod, qy);
                qz = fmaf(a.z, prod, qz);
                qw = fmaf(a.w, prod, qw);
                ++p;
            }
        }
    }

    // partial logits: W[o, pidx*4 + w]
    float lg[10];
    const float4* Wp = (const float4*)Wm;
#pragma unroll
    for (int o = 0; o < 10; ++o) {
        const float4 wv = Wp[o * 196 + pidx];
        lg[o] = mask * fmaf(qx, wv.x, fmaf(qy, wv.y, fmaf(qz, wv.z, qw * wv.w)));
    }

    // block reduction
#pragma unroll
    for (int off = 32; off; off >>= 1) {
#pragma unroll
        for (int o = 0; o < 10; ++o) lg[o] += __shfl_down(lg[o], off, 64);
    }
    const int lane = tid & 63, wid = tid >> 6;
    if (lane == 0) {
#pragma unroll
        for (int o = 0; o < 10; ++o) red[wid][o] = lg[o];
    }
    __syncthreads();
    if (tid == 0) {
        float logits[10];
        float mx = -1e30f;
#pragma unroll
        for (int o = 0; o < 10; ++o) {
            logits[o] = red[0][o] + red[1][o] + red[2][o] + red[3][o] + bv[o];
            mx = fmaxf(mx, logits[o]);
        }
        float se = 0.f;
#pragma unroll
        for (int o = 0; o < 10; ++o) se += expf(logits[o] - mx);
        const float lse = mx + logf(se);
#pragma unroll
        for (int o = 0; o < 10; ++o) out[b * 10 + o] = logits[o] - lse;
    }
}

extern "C" void kernel_launch(void* const* d_in, const int* in_sizes, int n_in,
                              void* d_out, int out_size, void* d_ws, size_t ws_size,
                              hipStream_t stream) {
    const float* x      = (const float*)d_in[0];  // [B,1,28,28]
    const float* params = (const float*)d_in[1];  // [3,4,3]
    const float* Wm     = (const float*)d_in[2];  // [10,784]
    const float* bv     = (const float*)d_in[3];  // [10]
    float* out          = (float*)d_out;          // [B,10]
    float* A2           = (float*)d_ws;           // [136,4]

    const int B = in_sizes[0] / 784;
    quanv_prep_kernel<<<1, 256, 0, stream>>>(params, A2);
    quanv_main_kernel<<<B, 256, 0, stream>>>(x, A2, Wm, bv, out);
}

// Round 3
// 23.825 us; speedup vs baseline: 1.1467x; 1.1295x over previous
//
#include <hip/hip_runtime.h>
#include <math.h>

// Pair enumeration (a<=b): P -> (PA[P], PB[P])
__device__ static const int PAIR_A[10] = {0,0,0,0,1,1,1,2,2,3};
__device__ static const int PAIR_B[10] = {0,1,2,3,1,2,3,2,3,3};

// ---------------------------------------------------------------------------
// Prep kernel (1 block, 64 threads = 1 wave):
//  Phase A: 36 lanes compute all gate sincos in parallel (native).
//  Phase B: 12 lanes form 2x2 gate matrices in LDS.
//  Phase C: 16 lanes build U columns (register butterflies, gates from LDS).
//  Phase D: A_w = Re(U^dag Z_w U) into LDS.
//  Phase E: C tensor [P][Q][w] (10x10x4, symmetry factors folded) to global.
// ---------------------------------------------------------------------------
__global__ __launch_bounds__(64) void quanv_prep_kernel(
    const float* __restrict__ params,  // [3,4,3]
    float* __restrict__ C4g)           // [100*4]
{
    __shared__ float sc[12][3][2];     // [gate][angle][{sin,cos}]
    __shared__ float gm[12][8];        // m00r,m00i,m01r,m01i,m10r,m10i,m11r,m11i
    __shared__ float Ur[16][17];
    __shared__ float Ui[16][17];
    __shared__ float Amat[4][16][16];

    const int tid = threadIdx.x;

    // Phase A: parallel sincos
    if (tid < 36) {
        const int g = tid / 3, a = tid % 3;
        const float phi = params[g * 3 + 0];
        const float th  = params[g * 3 + 1];
        const float om  = params[g * 3 + 2];
        const float ang = (a == 0) ? 0.5f * (phi + om)
                        : (a == 1) ? 0.5f * (phi - om)
                                   : 0.5f * th;
        sc[g][a][0] = __sinf(ang);
        sc[g][a][1] = __cosf(ang);
    }
    __syncthreads();

    // Phase B: gate matrices
    if (tid < 12) {
        const float sa = sc[tid][0][0], ca = sc[tid][0][1];
        const float sb = sc[tid][1][0], cb = sc[tid][1][1];
        const float st = sc[tid][2][0], ct = sc[tid][2][1];
        gm[tid][0] =  ct * ca; gm[tid][1] = -ct * sa;   // m00
        gm[tid][2] = -st * cb; gm[tid][3] = -st * sb;   // m01
        gm[tid][4] =  st * cb; gm[tid][5] = -st * sb;   // m10
        gm[tid][6] =  ct * ca; gm[tid][7] =  ct * sa;   // m11
    }
    __syncthreads();

    // Phase C: build U columns
    if (tid < 16) {
        const int col = tid;
        float sr[16], si[16];
#pragma unroll
        for (int k = 0; k < 16; ++k) { sr[k] = (k == col) ? 1.f : 0.f; si[k] = 0.f; }

#pragma unroll
        for (int l = 0; l < 3; ++l) {
#pragma unroll
            for (int w = 0; w < 4; ++w) {
                const int g = l * 4 + w;
                const float m00r = gm[g][0], m00i = gm[g][1];
                const float m01r = gm[g][2], m01i = gm[g][3];
                const float m10r = gm[g][4], m10i = gm[g][5];
                const float m11r = gm[g][6], m11i = gm[g][7];
                const int m = 8 >> w;  // wire 0 = MSB
#pragma unroll
                for (int i = 0; i < 16; ++i) {
                    if (!(i & m)) {
                        const int i1 = i | m;
                        const float a0r = sr[i],  a0i = si[i];
                        const float a1r = sr[i1], a1i = si[i1];
                        sr[i]  = m00r * a0r - m00i * a0i + m01r * a1r - m01i * a1i;
                        si[i]  = m00r * a0i + m00i * a0r + m01r * a1i + m01i * a1r;
                        sr[i1] = m10r * a0r - m10i * a0i + m11r * a1r - m11i * a1i;
                        si[i1] = m10r * a0i + m10i * a0r + m11r * a1i + m11i * a1r;
                    }
                }
            }
            const int r = (l % 3) + 1;
#pragma unroll
            for (int w = 0; w < 4; ++w) {
                const int cm = 8 >> w;
                const int tm = 8 >> ((w + r) & 3);
#pragma unroll
                for (int i = 0; i < 16; ++i) {
                    if ((i & cm) && !(i & tm)) {
                        const int i1 = i | tm;
                        const float tr = sr[i], ti = si[i];
                        sr[i]  = sr[i1]; si[i]  = si[i1];
                        sr[i1] = tr;     si[i1] = ti;
                    }
                }
            }
        }
#pragma unroll
        for (int k = 0; k < 16; ++k) { Ur[k][col] = sr[k]; Ui[k][col] = si[k]; }
    }
    __syncthreads();

    // Phase D: A[w][i][j] = sum_k sign_w(k) * Re(conj(U[k][i]) U[k][j])
    for (int e = tid; e < 256; e += 64) {
        const int i = e >> 4, j = e & 15;
        float a0 = 0.f, a1 = 0.f, a2 = 0.f, a3 = 0.f;
#pragma unroll
        for (int k = 0; k < 16; ++k) {
            const float pr = Ur[k][i] * Ur[k][j] + Ui[k][i] * Ui[k][j];
            if (k & 8) a0 -= pr; else a0 += pr;
            if (k & 4) a1 -= pr; else a1 += pr;
            if (k & 2) a2 -= pr; else a2 += pr;
            if (k & 1) a3 -= pr; else a3 += pr;
        }
        Amat[0][i][j] = a0; Amat[1][i][j] = a1;
        Amat[2][i][j] = a2; Amat[3][i][j] = a3;
    }
    __syncthreads();

    // Phase E: C tensor
    for (int e = tid; e < 400; e += 64) {
        const int w = e & 3, pq = e >> 2;     // pq in [0,100)
        const int P = pq / 10, Q = pq % 10;
        const int a = PAIR_A[P], b = PAIR_B[P];
        const int c = PAIR_A[Q], d = PAIR_B[Q];
        float val;
        if (a == b && c == d)      val = Amat[w][4 * a + c][4 * a + c];
        else if (a == b)           val = 2.f * Amat[w][4 * a + c][4 * a + d];
        else if (c == d)           val = 2.f * Amat[w][4 * a + c][4 * b + c];
        else                       val = 2.f * (Amat[w][4 * a + c][4 * b + d] +
                                                Amat[w][4 * a + d][4 * b + c]);
        C4g[pq * 4 + w] = val;
    }
}

// ---------------------------------------------------------------------------
// Main kernel: one block per image, thread = patch.
// q_w = sum_{P,Q} C_w[P][Q] * T_P * U_Q  (C read via wave-uniform scalar loads)
// ---------------------------------------------------------------------------
__global__ __launch_bounds__(256) void quanv_main_kernel(
    const float* __restrict__ x,       // [B,784]
    const float* __restrict__ C4g,     // [100*4]
    const float* __restrict__ Wm,      // [10,784]
    const float* __restrict__ bv,      // [10]
    float* __restrict__ out)           // [B,10]
{
    __shared__ float red[4][10];

    const int tid = threadIdx.x;
    const int b   = blockIdx.x;
    const float mask = (tid < 196) ? 1.f : 0.f;
    const int pidx = (tid < 196) ? tid : 195;

    const int pi = pidx / 14, pj = pidx % 14;
    const float* xb = x + b * 784 + pi * 56 + pj * 2;
    const float2 r0 = *(const float2*)(xb);
    const float2 r1 = *(const float2*)(xb + 28);

    // half-angles in [0, 0.5) rad -> native sin/cos safe
    const float h0 = 0.5f * r0.x, h1 = 0.5f * r0.y;
    const float h2 = 0.5f * r1.x, h3 = 0.5f * r1.y;
    const float s0 = __sinf(h0), c0 = __cosf(h0);
    const float s1 = __sinf(h1), c1 = __cosf(h1);
    const float s2 = __sinf(h2), c2 = __cosf(h2);
    const float s3 = __sinf(h3), c3 = __cosf(h3);

    float t[4], u[4];
    t[0] = c0 * c1; t[1] = c0 * s1; t[2] = s0 * c1; t[3] = s0 * s1;
    u[0] = c2 * c3; u[1] = c2 * s3; u[2] = s2 * c3; u[3] = s2 * s3;

    float T[10], U[10];
#pragma unroll
    for (int P = 0; P < 10; ++P) {
        T[P] = t[PAIR_A[P]] * t[PAIR_B[P]];
        U[P] = u[PAIR_A[P]] * u[PAIR_B[P]];
    }

    float qx = 0.f, qy = 0.f, qz = 0.f, qw = 0.f;
    const float4* __restrict__ C4 = (const float4*)C4g;
#pragma unroll
    for (int P = 0; P < 10; ++P) {
        float sx = 0.f, sy = 0.f, sz = 0.f, sw = 0.f;
#pragma unroll
        for (int Q = 0; Q < 10; ++Q) {
            const float4 cc = C4[P * 10 + Q];
            sx = fmaf(cc.x, U[Q], sx);
            sy = fmaf(cc.y, U[Q], sy);
            sz = fmaf(cc.z, U[Q], sz);
            sw = fmaf(cc.w, U[Q], sw);
        }
        qx = fmaf(T[P], sx, qx);
        qy = fmaf(T[P], sy, qy);
        qz = fmaf(T[P], sz, qz);
        qw = fmaf(T[P], sw, qw);
    }

    // partial logits: W[o, pidx*4 + w]
    float lg[10];
    const float4* Wp = (const float4*)Wm;
#pragma unroll
    for (int o = 0; o < 10; ++o) {
        const float4 wv = Wp[o * 196 + pidx];
        lg[o] = mask * fmaf(qx, wv.x, fmaf(qy, wv.y, fmaf(qz, wv.z, qw * wv.w)));
    }

    // block reduction
#pragma unroll
    for (int off = 32; off; off >>= 1) {
#pragma unroll
        for (int o = 0; o < 10; ++o) lg[o] += __shfl_down(lg[o], off, 64);
    }
    const int lane = tid & 63, wid = tid >> 6;
    if (lane == 0) {
#pragma unroll
        for (int o = 0; o < 10; ++o) red[wid][o] = lg[o];
    }
    __syncthreads();
    if (tid == 0) {
        float logits[10];
        float mx = -1e30f;
#pragma unroll
        for (int o = 0; o < 10; ++o) {
            logits[o] = red[0][o] + red[1][o] + red[2][o] + red[3][o] + bv[o];
            mx = fmaxf(mx, logits[o]);
        }
        float se = 0.f;
#pragma unroll
        for (int o = 0; o < 10; ++o) se += expf(logits[o] - mx);
        const float lse = mx + logf(se);
#pragma unroll
        for (int o = 0; o < 10; ++o) out[b * 10 + o] = logits[o] - lse;
    }
}

extern "C" void kernel_launch(void* const* d_in, const int* in_sizes, int n_in,
                              void* d_out, int out_size, void* d_ws, size_t ws_size,
                              hipStream_t stream) {
    const float* x      = (const float*)d_in[0];  // [B,1,28,28]
    const float* params = (const float*)d_in[1];  // [3,4,3]
    const float* Wm     = (const float*)d_in[2];  // [10,784]
    const float* bv     = (const float*)d_in[3];  // [10]
    float* out          = (float*)d_out;          // [B,10]
    float* C4g          = (float*)d_ws;           // [400]

    const int B = in_sizes[0] / 784;
    quanv_prep_kernel<<<1, 64, 0, stream>>>(params, C4g);
    quanv_main_kernel<<<B, 256, 0, stream>>>(x, C4g, Wm, bv, out);
}

// Round 4
// 17.691 us; speedup vs baseline: 1.5443x; 1.3467x over previous
//
#include <hip/hip_runtime.h>
#include <math.h>

#define QB 2  // images per block

// Pair enumeration (a<=b): P -> (PAIR_A[P], PAIR_B[P])
__device__ static const int PAIR_A[10] = {0,0,0,0,1,1,1,2,2,3};
__device__ static const int PAIR_B[10] = {0,1,2,3,1,2,3,2,3,3};

// Fully fused: every block redundantly computes the fixed circuit tensor C
// (cheap, ~1us, deterministic and identical across blocks), then processes
// QB images (thread = patch position, both images per thread so each LDS
// broadcast of C feeds 2x the FMAs), then an LDS-transpose logits phase and
// per-image log_softmax. One launch, no inter-kernel dependency.
__global__ __launch_bounds__(256) void quanv_fused1_kernel(
    const float* __restrict__ x,       // [B,784]
    const float* __restrict__ params,  // [3,4,3]
    const float* __restrict__ Wm,      // [10,784]
    const float* __restrict__ bv,      // [10]
    float* __restrict__ out,           // [B,10]
    int B)
{
    __shared__ float sc[12][3][2];     // [gate][angle][{sin,cos}]
    __shared__ float gm[12][8];        // gate 2x2 complex matrices
    __shared__ float Ur[16][17];
    __shared__ float Ui[16][17];
    __shared__ float Amat[4][16][16];
    __shared__ float4 C4s[100];        // C[P][Q][w]
    __shared__ float q_lds[4][QB][196];// [w][img][patch]
    __shared__ float red[QB][10];

    const int tid  = threadIdx.x;
    const int img0 = blockIdx.x * QB;

    // ---- early x prefetch: HBM latency hides under prep ----
    const int pidx = (tid < 196) ? tid : 195;
    const int pi = pidx / 14, pj = pidx % 14;
    float2 r0[QB], r1[QB];
#pragma unroll
    for (int m = 0; m < QB; ++m) {
        const int img = min(img0 + m, B - 1);
        const float* xb = x + img * 784 + pi * 56 + pj * 2;
        r0[m] = *(const float2*)(xb);
        r1[m] = *(const float2*)(xb + 28);
    }

    // ---- Phase A: 36 lanes, all gate sincos in parallel ----
    if (tid < 36) {
        const int g = tid / 3, a = tid % 3;
        const float phi = params[g * 3 + 0];
        const float th  = params[g * 3 + 1];
        const float om  = params[g * 3 + 2];
        const float ang = (a == 0) ? 0.5f * (phi + om)
                        : (a == 1) ? 0.5f * (phi - om)
                                   : 0.5f * th;
        sc[g][a][0] = __sinf(ang);
        sc[g][a][1] = __cosf(ang);
    }
    __syncthreads();

    // ---- Phase B: gate matrices ----
    if (tid < 12) {
        const float sa = sc[tid][0][0], ca = sc[tid][0][1];
        const float sb = sc[tid][1][0], cb = sc[tid][1][1];
        const float st = sc[tid][2][0], ct = sc[tid][2][1];
        gm[tid][0] =  ct * ca; gm[tid][1] = -ct * sa;   // m00
        gm[tid][2] = -st * cb; gm[tid][3] = -st * sb;   // m01
        gm[tid][4] =  st * cb; gm[tid][5] = -st * sb;   // m10
        gm[tid][6] =  ct * ca; gm[tid][7] =  ct * sa;   // m11
    }
    __syncthreads();

    // ---- Phase C: 16 lanes build U columns (register butterflies) ----
    if (tid < 16) {
        const int col = tid;
        float sr[16], si[16];
#pragma unroll
        for (int k = 0; k < 16; ++k) { sr[k] = (k == col) ? 1.f : 0.f; si[k] = 0.f; }

#pragma unroll
        for (int l = 0; l < 3; ++l) {
#pragma unroll
            for (int w = 0; w < 4; ++w) {
                const int g = l * 4 + w;
                const float m00r = gm[g][0], m00i = gm[g][1];
                const float m01r = gm[g][2], m01i = gm[g][3];
                const float m10r = gm[g][4], m10i = gm[g][5];
                const float m11r = gm[g][6], m11i = gm[g][7];
                const int m = 8 >> w;  // wire 0 = MSB
#pragma unroll
                for (int i = 0; i < 16; ++i) {
                    if (!(i & m)) {
                        const int i1 = i | m;
                        const float a0r = sr[i],  a0i = si[i];
                        const float a1r = sr[i1], a1i = si[i1];
                        sr[i]  = m00r * a0r - m00i * a0i + m01r * a1r - m01i * a1i;
                        si[i]  = m00r * a0i + m00i * a0r + m01r * a1i + m01i * a1r;
                        sr[i1] = m10r * a0r - m10i * a0i + m11r * a1r - m11i * a1i;
                        si[i1] = m10r * a0i + m10i * a0r + m11r * a1i + m11i * a1r;
                    }
                }
            }
            const int r = (l % 3) + 1;
#pragma unroll
            for (int w = 0; w < 4; ++w) {
                const int cm = 8 >> w;
                const int tm = 8 >> ((w + r) & 3);
#pragma unroll
                for (int i = 0; i < 16; ++i) {
                    if ((i & cm) && !(i & tm)) {
                        const int i1 = i | tm;
                        const float tr = sr[i], ti = si[i];
                        sr[i]  = sr[i1]; si[i]  = si[i1];
                        sr[i1] = tr;     si[i1] = ti;
                    }
                }
            }
        }
#pragma unroll
        for (int k = 0; k < 16; ++k) { Ur[k][col] = sr[k]; Ui[k][col] = si[k]; }
    }
    __syncthreads();

    // ---- Phase D: A[w][i][j] = sum_k sign_w(k) Re(conj(U[k][i]) U[k][j]) ----
    {
        const int i = tid >> 4, j = tid & 15;   // 256 threads = all (i,j)
        float a0 = 0.f, a1 = 0.f, a2 = 0.f, a3 = 0.f;
#pragma unroll
        for (int k = 0; k < 16; ++k) {
            const float pr = Ur[k][i] * Ur[k][j] + Ui[k][i] * Ui[k][j];
            if (k & 8) a0 -= pr; else a0 += pr;
            if (k & 4) a1 -= pr; else a1 += pr;
            if (k & 2) a2 -= pr; else a2 += pr;
            if (k & 1) a3 -= pr; else a3 += pr;
        }
        Amat[0][i][j] = a0; Amat[1][i][j] = a1;
        Amat[2][i][j] = a2; Amat[3][i][j] = a3;
    }
    __syncthreads();

    // ---- Phase E: C tensor into LDS ----
    for (int e = tid; e < 400; e += 256) {
        const int w = e & 3, pq = e >> 2;
        const int P = pq / 10, Q = pq % 10;
        const int a = PAIR_A[P], b = PAIR_B[P];
        const int c = PAIR_A[Q], d = PAIR_B[Q];
        float val;
        if (a == b && c == d)      val = Amat[w][4 * a + c][4 * a + c];
        else if (a == b)           val = 2.f * Amat[w][4 * a + c][4 * a + d];
        else if (c == d)           val = 2.f * Amat[w][4 * a + c][4 * b + c];
        else                       val = 2.f * (Amat[w][4 * a + c][4 * b + d] +
                                                Amat[w][4 * a + d][4 * b + c]);
        ((float*)&C4s[pq])[w] = val;
    }
    __syncthreads();

    // ---- Patch phase: thread = patch position, QB images at once ----
    if (tid < 196) {
        float T[QB][10], U[QB][10];
#pragma unroll
        for (int m = 0; m < QB; ++m) {
            const float h0 = 0.5f * r0[m].x, h1 = 0.5f * r0[m].y;
            const float h2 = 0.5f * r1[m].x, h3 = 0.5f * r1[m].y;
            const float s0 = __sinf(h0), c0 = __cosf(h0);
            const float s1 = __sinf(h1), c1 = __cosf(h1);
            const float s2 = __sinf(h2), c2 = __cosf(h2);
            const float s3 = __sinf(h3), c3 = __cosf(h3);
            float t[4], u[4];
            t[0] = c0 * c1; t[1] = c0 * s1; t[2] = s0 * c1; t[3] = s0 * s1;
            u[0] = c2 * c3; u[1] = c2 * s3; u[2] = s2 * c3; u[3] = s2 * s3;
#pragma unroll
            for (int P = 0; P < 10; ++P) {
                T[m][P] = t[PAIR_A[P]] * t[PAIR_B[P]];
                U[m][P] = u[PAIR_A[P]] * u[PAIR_B[P]];
            }
        }

        float q[QB][4];
#pragma unroll
        for (int m = 0; m < QB; ++m)
#pragma unroll
            for (int w = 0; w < 4; ++w) q[m][w] = 0.f;

#pragma unroll
        for (int P = 0; P < 10; ++P) {
            float s[QB][4];
#pragma unroll
            for (int m = 0; m < QB; ++m)
#pragma unroll
                for (int w = 0; w < 4; ++w) s[m][w] = 0.f;
#pragma unroll
            for (int Q = 0; Q < 10; ++Q) {
                const float4 cc = C4s[P * 10 + Q];  // wave-uniform broadcast
#pragma unroll
                for (int m = 0; m < QB; ++m) {
                    const float uq = U[m][Q];
                    s[m][0] = fmaf(cc.x, uq, s[m][0]);
                    s[m][1] = fmaf(cc.y, uq, s[m][1]);
                    s[m][2] = fmaf(cc.z, uq, s[m][2]);
                    s[m][3] = fmaf(cc.w, uq, s[m][3]);
                }
            }
#pragma unroll
            for (int m = 0; m < QB; ++m) {
                const float tp = T[m][P];
                q[m][0] = fmaf(tp, s[m][0], q[m][0]);
                q[m][1] = fmaf(tp, s[m][1], q[m][1]);
                q[m][2] = fmaf(tp, s[m][2], q[m][2]);
                q[m][3] = fmaf(tp, s[m][3], q[m][3]);
            }
        }

#pragma unroll
        for (int m = 0; m < QB; ++m)
#pragma unroll
            for (int w = 0; w < 4; ++w) q_lds[w][m][tid] = q[m][w];
    }
    __syncthreads();

    // ---- Logits phase: 160 threads = (img, o, c), c in [0,8) ----
    if (tid < 160) {
        const int img = tid / 80, rem = tid % 80;
        const int o = rem >> 3, c = rem & 7;
        const float4* Wp = (const float4*)Wm;
        float acc = 0.f;
#pragma unroll
        for (int k = 0; k < 25; ++k) {
            const int p = c + 8 * k;
            if (p < 196) {
                const float4 wv = Wp[o * 196 + p];
                acc = fmaf(wv.x, q_lds[0][img][p],
                      fmaf(wv.y, q_lds[1][img][p],
                      fmaf(wv.z, q_lds[2][img][p],
                      fmaf(wv.w, q_lds[3][img][p], acc))));
            }
        }
        acc += __shfl_down(acc, 1, 64);
        acc += __shfl_down(acc, 2, 64);
        acc += __shfl_down(acc, 4, 64);
        if (c == 0) red[img][o] = acc + bv[o];
    }
    __syncthreads();

    // ---- Final: per-image log_softmax ----
    if (tid < QB) {
        const int img = img0 + tid;
        if (img < B) {
            float lo[10];
            float mx = -1e30f;
#pragma unroll
            for (int o = 0; o < 10; ++o) { lo[o] = red[tid][o]; mx = fmaxf(mx, lo[o]); }
            float se = 0.f;
#pragma unroll
            for (int o = 0; o < 10; ++o) se += __expf(lo[o] - mx);
            const float lse = mx + __logf(se);
#pragma unroll
            for (int o = 0; o < 10; ++o) out[img * 10 + o] = lo[o] - lse;
        }
    }
}

extern "C" void kernel_launch(void* const* d_in, const int* in_sizes, int n_in,
                              void* d_out, int out_size, void* d_ws, size_t ws_size,
                              hipStream_t stream) {
    const float* x      = (const float*)d_in[0];  // [B,1,28,28]
    const float* params = (const float*)d_in[1];  // [3,4,3]
    const float* Wm     = (const float*)d_in[2];  // [10,784]
    const float* bv     = (const float*)d_in[3];  // [10]
    float* out          = (float*)d_out;          // [B,10]

    const int B = in_sizes[0] / 784;
    const int nblk = (B + QB - 1) / QB;
    quanv_fused1_kernel<<<nblk, 256, 0, stream>>>(x, params, Wm, bv, out, B);
}

// Round 5
// 17.518 us; speedup vs baseline: 1.5596x; 1.0099x over previous
//
#include <hip/hip_runtime.h>
#include <math.h>

#define QB 4  // images per block

// Pair enumeration (a<=b): P -> (PAIR_A[P], PAIR_B[P])
__device__ static const int PAIR_A[10] = {0,0,0,0,1,1,1,2,2,3};
__device__ static const int PAIR_B[10] = {0,1,2,3,1,2,3,2,3,3};

__device__ __forceinline__ float2 pkfma(float2 a, float b, float2 c) {
    return make_float2(fmaf(a.x, b, c.x), fmaf(a.y, b, c.y));
}

// Fully fused, one launch. Every block redundantly computes the fixed circuit
// tensor C (prep parallelized: U-build is a 256-thread shfl butterfly network,
// ~170 instr critical path instead of ~1350 on 16 lanes), then processes QB
// images (thread = patch), LDS-transpose logits, per-image log_softmax.
__global__ __launch_bounds__(256) void quanv_fused2_kernel(
    const float* __restrict__ x,       // [B,784]
    const float* __restrict__ params,  // [3,4,3]
    const float* __restrict__ Wm,      // [10,784]
    const float* __restrict__ bv,      // [10]
    float* __restrict__ out,           // [B,10]
    int B)
{
    __shared__ float4 gm4[12][2];      // [gate][row-bit]{ar,ai,br,bi}
    __shared__ float Ur[16][17];
    __shared__ float Ui[16][17];
    __shared__ float Amat[4][16][16];
    __shared__ float4 C4s[100];        // C[P*10+Q][w]
    __shared__ float q_lds[4][QB][196];// [w][img][patch]
    __shared__ float red[QB][10];

    const int tid  = threadIdx.x;
    const int img0 = blockIdx.x * QB;

    // ---- early x prefetch: HBM latency hides under prep ----
    const int pidx = (tid < 196) ? tid : 195;
    const int pi = pidx / 14, pj = pidx % 14;
    float2 r0[QB], r1[QB];
#pragma unroll
    for (int m = 0; m < QB; ++m) {
        const int img = min(img0 + m, B - 1);
        const float* xb = x + img * 784 + pi * 56 + pj * 2;
        r0[m] = *(const float2*)(xb);
        r1[m] = *(const float2*)(xb + 28);
    }

    // ---- Phase AB: 12 lanes build gate matrices (native sincos) ----
    if (tid < 12) {
        const float phi = params[tid * 3 + 0];
        const float th  = params[tid * 3 + 1];
        const float om  = params[tid * 3 + 2];
        const float aa = 0.5f * (phi + om), ab = 0.5f * (phi - om), at = 0.5f * th;
        const float sa = __sinf(aa), ca = __cosf(aa);
        const float sb = __sinf(ab), cb = __cosf(ab);
        const float st = __sinf(at), ct = __cosf(at);
        // bit0 rows: s' = m00*s + m01*p ; bit1 rows: s' = m11*s + m10*p
        gm4[tid][0] = make_float4( ct * ca, -ct * sa, -st * cb, -st * sb);
        gm4[tid][1] = make_float4( ct * ca,  ct * sa,  st * cb, -st * sb);
    }
    __syncthreads();

    // ---- Phase C: build U via shfl butterflies, thread = (col,row) ----
    {
        const int col = tid >> 4, row = tid & 15;
        float sr = (row == col) ? 1.f : 0.f;
        float si = 0.f;
#pragma unroll
        for (int l = 0; l < 3; ++l) {
#pragma unroll
            for (int w = 0; w < 4; ++w) {
                const int g = l * 4 + w;
                const int m = 8 >> w;          // wire 0 = MSB
                const int bit = (row & m) ? 1 : 0;
                const float4 mm = gm4[g][bit]; // 2 distinct LDS addrs/wave
                const float pr = __shfl_xor(sr, m, 64);
                const float pi2 = __shfl_xor(si, m, 64);
                const float nsr = mm.x * sr - mm.y * si + mm.z * pr - mm.w * pi2;
                const float nsi = mm.x * si + mm.y * sr + mm.z * pi2 + mm.w * pr;
                sr = nsr; si = nsi;
            }
            const int r = (l % 3) + 1;
#pragma unroll
            for (int w = 0; w < 4; ++w) {
                const int cm = 8 >> w;
                const int tm = 8 >> ((w + r) & 3);
                const float pr = __shfl_xor(sr, tm, 64);
                const float pi2 = __shfl_xor(si, tm, 64);
                const bool take = (row & cm) != 0;
                sr = take ? pr : sr;
                si = take ? pi2 : si;
            }
        }
        Ur[row][col] = sr;
        Ui[row][col] = si;
    }
    __syncthreads();

    // ---- Phase D: A[w][i][j] = sum_k sign_w(k) Re(conj(U[k][i]) U[k][j]) ----
    {
        const int i = tid >> 4, j = tid & 15;
        float a0 = 0.f, a1 = 0.f, a2 = 0.f, a3 = 0.f;
#pragma unroll
        for (int k = 0; k < 16; ++k) {
            const float pr = Ur[k][i] * Ur[k][j] + Ui[k][i] * Ui[k][j];
            if (k & 8) a0 -= pr; else a0 += pr;
            if (k & 4) a1 -= pr; else a1 += pr;
            if (k & 2) a2 -= pr; else a2 += pr;
            if (k & 1) a3 -= pr; else a3 += pr;
        }
        Amat[0][i][j] = a0; Amat[1][i][j] = a1;
        Amat[2][i][j] = a2; Amat[3][i][j] = a3;
    }
    __syncthreads();

    // ---- Phase E: C tensor into LDS ----
    for (int e = tid; e < 400; e += 256) {
        const int w = e & 3, pq = e >> 2;
        const int P = pq / 10, Q = pq % 10;
        const int a = PAIR_A[P], b = PAIR_B[P];
        const int c = PAIR_A[Q], d = PAIR_B[Q];
        float val;
        if (a == b && c == d)      val = Amat[w][4 * a + c][4 * a + c];
        else if (a == b)           val = 2.f * Amat[w][4 * a + c][4 * a + d];
        else if (c == d)           val = 2.f * Amat[w][4 * a + c][4 * b + c];
        else                       val = 2.f * (Amat[w][4 * a + c][4 * b + d] +
                                                Amat[w][4 * a + d][4 * b + c]);
        ((float*)&C4s[pq])[w] = val;
    }
    __syncthreads();

    // ---- Patch phase: thread = patch position, QB images ----
    if (tid < 196) {
        float T[QB][10], U[QB][10];
#pragma unroll
        for (int m = 0; m < QB; ++m) {
            const float h0 = 0.5f * r0[m].x, h1 = 0.5f * r0[m].y;
            const float h2 = 0.5f * r1[m].x, h3 = 0.5f * r1[m].y;
            const float s0 = __sinf(h0), c0 = __cosf(h0);
            const float s1 = __sinf(h1), c1 = __cosf(h1);
            const float s2 = __sinf(h2), c2 = __cosf(h2);
            const float s3 = __sinf(h3), c3 = __cosf(h3);
            float t[4], u[4];
            t[0] = c0 * c1; t[1] = c0 * s1; t[2] = s0 * c1; t[3] = s0 * s1;
            u[0] = c2 * c3; u[1] = c2 * s3; u[2] = s2 * c3; u[3] = s2 * s3;
#pragma unroll
            for (int P = 0; P < 10; ++P) {
                T[m][P] = t[PAIR_A[P]] * t[PAIR_B[P]];
                U[m][P] = u[PAIR_A[P]] * u[PAIR_B[P]];
            }
        }

        float2 q01[QB], q23[QB];
#pragma unroll
        for (int m = 0; m < QB; ++m) { q01[m] = make_float2(0.f, 0.f); q23[m] = make_float2(0.f, 0.f); }

#pragma unroll
        for (int P = 0; P < 10; ++P) {
            float2 s01[QB], s23[QB];
#pragma unroll
            for (int m = 0; m < QB; ++m) { s01[m] = make_float2(0.f, 0.f); s23[m] = make_float2(0.f, 0.f); }
#pragma unroll
            for (int Q = 0; Q < 10; ++Q) {
                const float4 cc = C4s[P * 10 + Q];  // wave-uniform broadcast
                const float2 c01 = make_float2(cc.x, cc.y);
                const float2 c23 = make_float2(cc.z, cc.w);
#pragma unroll
                for (int m = 0; m < QB; ++m) {
                    const float uq = U[m][Q];
                    s01[m] = pkfma(c01, uq, s01[m]);
                    s23[m] = pkfma(c23, uq, s23[m]);
                }
            }
#pragma unroll
            for (int m = 0; m < QB; ++m) {
                const float tp = T[m][P];
                q01[m] = pkfma(s01[m], tp, q01[m]);
                q23[m] = pkfma(s23[m], tp, q23[m]);
            }
        }

#pragma unroll
        for (int m = 0; m < QB; ++m) {
            q_lds[0][m][tid] = q01[m].x;
            q_lds[1][m][tid] = q01[m].y;
            q_lds[2][m][tid] = q23[m].x;
            q_lds[3][m][tid] = q23[m].y;
        }
    }
    __syncthreads();

    // ---- Logits: 2 halves x 160 threads = (img, o, c), c in [0,8) ----
#pragma unroll
    for (int half = 0; half < 2; ++half) {
        if (tid < 160) {
            const int img = half * 2 + tid / 80;
            const int rem = tid % 80;
            const int o = rem >> 3, c = rem & 7;
            const float4* Wp = (const float4*)Wm;
            float acc = 0.f;
#pragma unroll
            for (int k = 0; k < 25; ++k) {
                const int p = c + 8 * k;
                if (p < 196) {
                    const float4 wv = Wp[o * 196 + p];
                    acc = fmaf(wv.x, q_lds[0][img][p],
                          fmaf(wv.y, q_lds[1][img][p],
                          fmaf(wv.z, q_lds[2][img][p],
                          fmaf(wv.w, q_lds[3][img][p], acc))));
                }
            }
            acc += __shfl_down(acc, 1, 64);
            acc += __shfl_down(acc, 2, 64);
            acc += __shfl_down(acc, 4, 64);
            if (c == 0) red[img][o] = acc + bv[o];
        }
    }
    __syncthreads();

    // ---- Final: per-image log_softmax ----
    if (tid < QB) {
        const int img = img0 + tid;
        if (img < B) {
            float lo[10];
            float mx = -1e30f;
#pragma unroll
            for (int o = 0; o < 10; ++o) { lo[o] = red[tid][o]; mx = fmaxf(mx, lo[o]); }
            float se = 0.f;
#pragma unroll
            for (int o = 0; o < 10; ++o) se += __expf(lo[o] - mx);
            const float lse = mx + __logf(se);
#pragma unroll
            for (int o = 0; o < 10; ++o) out[img * 10 + o] = lo[o] - lse;
        }
    }
}

extern "C" void kernel_launch(void* const* d_in, const int* in_sizes, int n_in,
                              void* d_out, int out_size, void* d_ws, size_t ws_size,
                              hipStream_t stream) {
    const float* x      = (const float*)d_in[0];  // [B,1,28,28]
    const float* params = (const float*)d_in[1];  // [3,4,3]
    const float* Wm     = (const float*)d_in[2];  // [10,784]
    const float* bv     = (const float*)d_in[3];  // [10]
    float* out          = (float*)d_out;          // [B,10]

    const int B = in_sizes[0] / 784;
    const int nblk = (B + QB - 1) / QB;
    quanv_fused2_kernel<<<nblk, 256, 0, stream>>>(x, params, Wm, bv, out, B);
}

// Round 6
// 13.686 us; speedup vs baseline: 1.9962x; 1.2800x over previous
//
#include <hip/hip_runtime.h>
#include <math.h>

#define QB 2  // images per block: 512 blocks -> 2 blocks/CU -> 2 waves/SIMD

// Pair enumeration (a<=b): P -> (PAIR_A[P], PAIR_B[P])
__device__ static const int PAIR_A[10] = {0,0,0,0,1,1,1,2,2,3};
__device__ static const int PAIR_B[10] = {0,1,2,3,1,2,3,2,3,3};

__device__ __forceinline__ float2 pkfma(float2 a, float b, float2 c) {
    return make_float2(fmaf(a.x, b, c.x), fmaf(a.y, b, c.y));
}

// Fully fused, one launch. Every block redundantly computes the fixed circuit
// tensor C (parallel prep: 256-thread shfl butterfly U-build), then processes
// QB images (thread = patch), LDS-transpose logits, per-image log_softmax.
__global__ __launch_bounds__(256) void quanv_fused3_kernel(
    const float* __restrict__ x,       // [B,784]
    const float* __restrict__ params,  // [3,4,3]
    const float* __restrict__ Wm,      // [10,784]
    const float* __restrict__ bv,      // [10]
    float* __restrict__ out,           // [B,10]
    int B)
{
    __shared__ float4 gm4[12][2];      // [gate][row-bit]{ar,ai,br,bi}
    __shared__ float Ur[16][17];
    __shared__ float Ui[16][17];
    __shared__ float Amat[4][16][16];
    __shared__ float4 C4s[100];        // C[P*10+Q][w]
    __shared__ float q_lds[4][QB][196];// [w][img][patch]
    __shared__ float red[QB][10];

    const int tid  = threadIdx.x;
    const int img0 = blockIdx.x * QB;

    // ---- early x prefetch: HBM latency hides under prep ----
    const int pidx = (tid < 196) ? tid : 195;
    const int pi = pidx / 14, pj = pidx % 14;
    float2 r0[QB], r1[QB];
#pragma unroll
    for (int m = 0; m < QB; ++m) {
        const int img = min(img0 + m, B - 1);
        const float* xb = x + img * 784 + pi * 56 + pj * 2;
        r0[m] = *(const float2*)(xb);
        r1[m] = *(const float2*)(xb + 28);
    }

    // ---- Phase AB: 12 lanes build gate matrices (native sincos) ----
    if (tid < 12) {
        const float phi = params[tid * 3 + 0];
        const float th  = params[tid * 3 + 1];
        const float om  = params[tid * 3 + 2];
        const float aa = 0.5f * (phi + om), ab = 0.5f * (phi - om), at = 0.5f * th;
        const float sa = __sinf(aa), ca = __cosf(aa);
        const float sb = __sinf(ab), cb = __cosf(ab);
        const float st = __sinf(at), ct = __cosf(at);
        // bit0 rows: s' = m00*s + m01*p ; bit1 rows: s' = m11*s + m10*p
        gm4[tid][0] = make_float4( ct * ca, -ct * sa, -st * cb, -st * sb);
        gm4[tid][1] = make_float4( ct * ca,  ct * sa,  st * cb, -st * sb);
    }
    __syncthreads();

    // ---- Phase C: build U via shfl butterflies, thread = (col,row) ----
    {
        const int col = tid >> 4, row = tid & 15;
        float sr = (row == col) ? 1.f : 0.f;
        float si = 0.f;
#pragma unroll
        for (int l = 0; l < 3; ++l) {
#pragma unroll
            for (int w = 0; w < 4; ++w) {
                const int g = l * 4 + w;
                const int m = 8 >> w;          // wire 0 = MSB
                const int bit = (row & m) ? 1 : 0;
                const float4 mm = gm4[g][bit]; // 2 distinct LDS addrs/wave
                const float pr = __shfl_xor(sr, m, 64);
                const float pi2 = __shfl_xor(si, m, 64);
                const float nsr = mm.x * sr - mm.y * si + mm.z * pr - mm.w * pi2;
                const float nsi = mm.x * si + mm.y * sr + mm.z * pi2 + mm.w * pr;
                sr = nsr; si = nsi;
            }
            const int r = (l % 3) + 1;
#pragma unroll
            for (int w = 0; w < 4; ++w) {
                const int cm = 8 >> w;
                const int tm = 8 >> ((w + r) & 3);
                const float pr = __shfl_xor(sr, tm, 64);
                const float pi2 = __shfl_xor(si, tm, 64);
                const bool take = (row & cm) != 0;
                sr = take ? pr : sr;
                si = take ? pi2 : si;
            }
        }
        Ur[row][col] = sr;
        Ui[row][col] = si;
    }
    __syncthreads();

    // ---- Phase D: A[w][i][j] = sum_k sign_w(k) Re(conj(U[k][i]) U[k][j]) ----
    {
        const int i = tid >> 4, j = tid & 15;
        float a0 = 0.f, a1 = 0.f, a2 = 0.f, a3 = 0.f;
#pragma unroll
        for (int k = 0; k < 16; ++k) {
            const float pr = Ur[k][i] * Ur[k][j] + Ui[k][i] * Ui[k][j];
            if (k & 8) a0 -= pr; else a0 += pr;
            if (k & 4) a1 -= pr; else a1 += pr;
            if (k & 2) a2 -= pr; else a2 += pr;
            if (k & 1) a3 -= pr; else a3 += pr;
        }
        Amat[0][i][j] = a0; Amat[1][i][j] = a1;
        Amat[2][i][j] = a2; Amat[3][i][j] = a3;
    }
    __syncthreads();

    // ---- Phase E: C tensor into LDS ----
    for (int e = tid; e < 400; e += 256) {
        const int w = e & 3, pq = e >> 2;
        const int P = pq / 10, Q = pq % 10;
        const int a = PAIR_A[P], b = PAIR_B[P];
        const int c = PAIR_A[Q], d = PAIR_B[Q];
        float val;
        if (a == b && c == d)      val = Amat[w][4 * a + c][4 * a + c];
        else if (a == b)           val = 2.f * Amat[w][4 * a + c][4 * a + d];
        else if (c == d)           val = 2.f * Amat[w][4 * a + c][4 * b + c];
        else                       val = 2.f * (Amat[w][4 * a + c][4 * b + d] +
                                                Amat[w][4 * a + d][4 * b + c]);
        ((float*)&C4s[pq])[w] = val;
    }
    __syncthreads();

    // ---- Patch phase: thread = patch position, QB images ----
    if (tid < 196) {
        float T[QB][10], U[QB][10];
#pragma unroll
        for (int m = 0; m < QB; ++m) {
            const float h0 = 0.5f * r0[m].x, h1 = 0.5f * r0[m].y;
            const float h2 = 0.5f * r1[m].x, h3 = 0.5f * r1[m].y;
            const float s0 = __sinf(h0), c0 = __cosf(h0);
            const float s1 = __sinf(h1), c1 = __cosf(h1);
            const float s2 = __sinf(h2), c2 = __cosf(h2);
            const float s3 = __sinf(h3), c3 = __cosf(h3);
            float t[4], u[4];
            t[0] = c0 * c1; t[1] = c0 * s1; t[2] = s0 * c1; t[3] = s0 * s1;
            u[0] = c2 * c3; u[1] = c2 * s3; u[2] = s2 * c3; u[3] = s2 * s3;
#pragma unroll
            for (int P = 0; P < 10; ++P) {
                T[m][P] = t[PAIR_A[P]] * t[PAIR_B[P]];
                U[m][P] = u[PAIR_A[P]] * u[PAIR_B[P]];
            }
        }

        float2 q01[QB], q23[QB];
#pragma unroll
        for (int m = 0; m < QB; ++m) { q01[m] = make_float2(0.f, 0.f); q23[m] = make_float2(0.f, 0.f); }

#pragma unroll
        for (int P = 0; P < 10; ++P) {
            float2 s01[QB], s23[QB];
#pragma unroll
            for (int m = 0; m < QB; ++m) { s01[m] = make_float2(0.f, 0.f); s23[m] = make_float2(0.f, 0.f); }
#pragma unroll
            for (int Q = 0; Q < 10; ++Q) {
                const float4 cc = C4s[P * 10 + Q];  // wave-uniform broadcast
                const float2 c01 = make_float2(cc.x, cc.y);
                const float2 c23 = make_float2(cc.z, cc.w);
#pragma unroll
                for (int m = 0; m < QB; ++m) {
                    const float uq = U[m][Q];
                    s01[m] = pkfma(c01, uq, s01[m]);
                    s23[m] = pkfma(c23, uq, s23[m]);
                }
            }
#pragma unroll
            for (int m = 0; m < QB; ++m) {
                const float tp = T[m][P];
                q01[m] = pkfma(s01[m], tp, q01[m]);
                q23[m] = pkfma(s23[m], tp, q23[m]);
            }
        }

#pragma unroll
        for (int m = 0; m < QB; ++m) {
            q_lds[0][m][tid] = q01[m].x;
            q_lds[1][m][tid] = q01[m].y;
            q_lds[2][m][tid] = q23[m].x;
            q_lds[3][m][tid] = q23[m].y;
        }
    }
    __syncthreads();

    // ---- Logits: 160 threads = (img, o, c), img in [0,2), c in [0,8) ----
    if (tid < 160) {
        const int img = tid / 80, rem = tid % 80;
        const int o = rem >> 3, c = rem & 7;
        const float4* Wp = (const float4*)Wm;
        float acc = 0.f;
#pragma unroll
        for (int k = 0; k < 25; ++k) {
            const int p = c + 8 * k;
            if (p < 196) {
                const float4 wv = Wp[o * 196 + p];
                acc = fmaf(wv.x, q_lds[0][img][p],
                      fmaf(wv.y, q_lds[1][img][p],
                      fmaf(wv.z, q_lds[2][img][p],
                      fmaf(wv.w, q_lds[3][img][p], acc))));
            }
        }
        acc += __shfl_down(acc, 1, 64);
        acc += __shfl_down(acc, 2, 64);
        acc += __shfl_down(acc, 4, 64);
        if (c == 0) red[img][o] = acc + bv[o];
    }
    __syncthreads();

    // ---- Final: per-image log_softmax ----
    if (tid < QB) {
        const int img = img0 + tid;
        if (img < B) {
            float lo[10];
            float mx = -1e30f;
#pragma unroll
            for (int o = 0; o < 10; ++o) { lo[o] = red[tid][o]; mx = fmaxf(mx, lo[o]); }
            float se = 0.f;
#pragma unroll
            for (int o = 0; o < 10; ++o) se += __expf(lo[o] - mx);
            const float lse = mx + __logf(se);
#pragma unroll
            for (int o = 0; o < 10; ++o) out[img * 10 + o] = lo[o] - lse;
        }
    }
}

extern "C" void kernel_launch(void* const* d_in, const int* in_sizes, int n_in,
                              void* d_out, int out_size, void* d_ws, size_t ws_size,
                              hipStream_t stream) {
    const float* x      = (const float*)d_in[0];  // [B,1,28,28]
    const float* params = (const float*)d_in[1];  // [3,4,3]
    const float* Wm     = (const float*)d_in[2];  // [10,784]
    const float* bv     = (const float*)d_in[3];  // [10]
    float* out          = (float*)d_out;          // [B,10]

    const int B = in_sizes[0] / 784;
    const int nblk = (B + QB - 1) / QB;
    quanv_fused3_kernel<<<nblk, 256, 0, stream>>>(x, params, Wm, bv, out, B);
}

// Round 7
// 13.176 us; speedup vs baseline: 2.0735x; 1.0387x over previous
//
#include <hip/hip_runtime.h>
#include <math.h>

#define IPB 2     // images per block
#define BLK 512   // threads per block: patch phase = one image per thread

__device__ __forceinline__ float2 pkfma(float2 a, float b, float2 c) {
    return make_float2(fmaf(a.x, b, c.x), fmaf(a.y, b, c.y));
}

// Fully fused, one launch, 512-thread blocks, 2 images/block (thread = (img,patch)).
// Grid 512 -> 2 blocks/CU -> 16 waves/CU = 4 waves/SIMD of latency hiding.
__global__ __launch_bounds__(BLK) void quanv_fused4_kernel(
    const float* __restrict__ x,       // [B,784]
    const float* __restrict__ params,  // [3,4,3]
    const float* __restrict__ Wm,      // [10,784]
    const float* __restrict__ bv,      // [10]
    float* __restrict__ out,           // [B,10]
    int B)
{
    __shared__ float4 gm4[12][2];      // [gate][row-bit]{ar,ai,br,bi}
    __shared__ float Ur[16][17];
    __shared__ float Ui[16][17];
    __shared__ float Amat[4][16][16];
    __shared__ float4 C4s[100];        // C[P*10+Q][w]
    __shared__ int   pa_s[10], pb_s[10];
    __shared__ float q_lds[4][IPB][196];
    __shared__ float red[IPB][10];

    const int tid  = threadIdx.x;
    const int img0 = blockIdx.x * IPB;

    // ---- early x prefetch (thread = (img_local, patch)) ----
    const int iml  = (tid >= 196) ? 1 : 0;
    const int p_raw = tid - iml * 196;
    const int pidx = (tid < 392) ? p_raw : 0;
    const int pi = pidx / 14, pj = pidx % 14;
    float2 r0, r1;
    {
        const int img = min(img0 + iml, B - 1);
        const float* xb = x + img * 784 + pi * 56 + pj * 2;
        r0 = *(const float2*)(xb);
        r1 = *(const float2*)(xb + 28);
    }

    // ---- Phase AB: 12 lanes build gate matrices; 10 lanes fill pair tables ----
    if (tid < 12) {
        const float phi = params[tid * 3 + 0];
        const float th  = params[tid * 3 + 1];
        const float om  = params[tid * 3 + 2];
        const float aa = 0.5f * (phi + om), ab = 0.5f * (phi - om), at = 0.5f * th;
        const float sa = __sinf(aa), ca = __cosf(aa);
        const float sb = __sinf(ab), cb = __cosf(ab);
        const float st = __sinf(at), ct = __cosf(at);
        gm4[tid][0] = make_float4( ct * ca, -ct * sa, -st * cb, -st * sb);
        gm4[tid][1] = make_float4( ct * ca,  ct * sa,  st * cb, -st * sb);
    } else if (tid >= 64 && tid < 74) {
        const int P = tid - 64;
        // pairs (a<=b) row-major: P -> (a,b)
        const int pa = (P < 4) ? 0 : (P < 7) ? 1 : (P < 9) ? 2 : 3;
        const int pb = (P < 4) ? P : (P < 7) ? P - 3 : (P < 9) ? P - 5 : 3;
        pa_s[P] = pa; pb_s[P] = pb;
    }
    __syncthreads();

    // ---- Phase C: build U via shfl butterflies, threads 0..255 = (col,row) ----
    if (tid < 256) {
        const int col = tid >> 4, row = tid & 15;
        float sr = (row == col) ? 1.f : 0.f;
        float si = 0.f;
#pragma unroll
        for (int l = 0; l < 3; ++l) {
#pragma unroll
            for (int w = 0; w < 4; ++w) {
                const int g = l * 4 + w;
                const int m = 8 >> w;          // wire 0 = MSB
                const int bit = (row & m) ? 1 : 0;
                const float4 mm = gm4[g][bit];
                const float pr  = __shfl_xor(sr, m, 64);
                const float pi2 = __shfl_xor(si, m, 64);
                const float nsr = mm.x * sr - mm.y * si + mm.z * pr - mm.w * pi2;
                const float nsi = mm.x * si + mm.y * sr + mm.z * pi2 + mm.w * pr;
                sr = nsr; si = nsi;
            }
            const int r = (l % 3) + 1;
#pragma unroll
            for (int w = 0; w < 4; ++w) {
                const int cm = 8 >> w;
                const int tm = 8 >> ((w + r) & 3);
                const float pr  = __shfl_xor(sr, tm, 64);
                const float pi2 = __shfl_xor(si, tm, 64);
                const bool take = (row & cm) != 0;
                sr = take ? pr : sr;
                si = take ? pi2 : si;
            }
        }
        Ur[row][col] = sr;
        Ui[row][col] = si;
    }
    __syncthreads();

    // ---- Phase D: A[w][i][j] (threads 0..255 = (i,j)) ----
    if (tid < 256) {
        const int i = tid >> 4, j = tid & 15;
        float a0 = 0.f, a1 = 0.f, a2 = 0.f, a3 = 0.f;
#pragma unroll
        for (int k = 0; k < 16; ++k) {
            const float pr = Ur[k][i] * Ur[k][j] + Ui[k][i] * Ui[k][j];
            if (k & 8) a0 -= pr; else a0 += pr;
            if (k & 4) a1 -= pr; else a1 += pr;
            if (k & 2) a2 -= pr; else a2 += pr;
            if (k & 1) a3 -= pr; else a3 += pr;
        }
        Amat[0][i][j] = a0; Amat[1][i][j] = a1;
        Amat[2][i][j] = a2; Amat[3][i][j] = a3;
    }
    __syncthreads();

    // ---- Phase E: C tensor into LDS (400 items, one per thread) ----
    if (tid < 400) {
        const int w = tid & 3, pq = tid >> 2;
        const int P = pq / 10, Q = pq % 10;
        const int a = pa_s[P], b = pb_s[P];
        const int c = pa_s[Q], d = pb_s[Q];
        // val = s*(A[4a+c][4b+d] + A[4a+d][4b+c]), s = 0.5 * 2^{(a!=b)+(c!=d)}
        const float s = 0.5f * (float)(1 << ((a != b) + (c != d)));
        const float val = s * (Amat[w][4 * a + c][4 * b + d] +
                               Amat[w][4 * a + d][4 * b + c]);
        ((float*)&C4s[pq])[w] = val;
    }
    __syncthreads();

    // ---- Patch phase: threads 0..391, one image per thread ----
    if (tid < 392) {
        const float h0 = 0.5f * r0.x, h1 = 0.5f * r0.y;
        const float h2 = 0.5f * r1.x, h3 = 0.5f * r1.y;
        const float s0 = __sinf(h0), c0 = __cosf(h0);
        const float s1 = __sinf(h1), c1 = __cosf(h1);
        const float s2 = __sinf(h2), c2 = __cosf(h2);
        const float s3 = __sinf(h3), c3 = __cosf(h3);
        float t[4], u[4];
        t[0] = c0 * c1; t[1] = c0 * s1; t[2] = s0 * c1; t[3] = s0 * s1;
        u[0] = c2 * c3; u[1] = c2 * s3; u[2] = s2 * c3; u[3] = s2 * s3;

        // pair products, order: (0,0)(0,1)(0,2)(0,3)(1,1)(1,2)(1,3)(2,2)(2,3)(3,3)
        float T[10], U[10];
        {
            int P = 0;
#pragma unroll
            for (int a = 0; a < 4; ++a)
#pragma unroll
                for (int b2 = a; b2 < 4; ++b2) {
                    T[P] = t[a] * t[b2];
                    U[P] = u[a] * u[b2];
                    ++P;
                }
        }

        float2 q01 = make_float2(0.f, 0.f), q23 = make_float2(0.f, 0.f);
#pragma unroll
        for (int P = 0; P < 10; ++P) {
            float2 s01 = make_float2(0.f, 0.f), s23 = make_float2(0.f, 0.f);
#pragma unroll
            for (int Q = 0; Q < 10; ++Q) {
                const float4 cc = C4s[P * 10 + Q];  // wave-uniform broadcast
                s01 = pkfma(make_float2(cc.x, cc.y), U[Q], s01);
                s23 = pkfma(make_float2(cc.z, cc.w), U[Q], s23);
            }
            q01 = pkfma(s01, T[P], q01);
            q23 = pkfma(s23, T[P], q23);
        }

        q_lds[0][iml][p_raw] = q01.x;
        q_lds[1][iml][p_raw] = q01.y;
        q_lds[2][iml][p_raw] = q23.x;
        q_lds[3][iml][p_raw] = q23.y;
    }
    __syncthreads();

    // ---- Logits: 320 threads = (img, o, c), c in [0,16) ----
    if (tid < 320) {
        const int img = tid / 160, rem = tid % 160;
        const int o = rem >> 4, c = rem & 15;
        const float4* Wp = (const float4*)Wm;
        float acc = 0.f;
#pragma unroll
        for (int k = 0; k < 13; ++k) {
            const int p = c + 16 * k;
            if (p < 196) {
                const float4 wv = Wp[o * 196 + p];
                acc = fmaf(wv.x, q_lds[0][img][p],
                      fmaf(wv.y, q_lds[1][img][p],
                      fmaf(wv.z, q_lds[2][img][p],
                      fmaf(wv.w, q_lds[3][img][p], acc))));
            }
        }
        acc += __shfl_down(acc, 1, 16);
        acc += __shfl_down(acc, 2, 16);
        acc += __shfl_down(acc, 4, 16);
        acc += __shfl_down(acc, 8, 16);
        if (c == 0) red[img][o] = acc + bv[o];
    }
    __syncthreads();

    // ---- Final: per-image log_softmax ----
    if (tid < IPB) {
        const int img = img0 + tid;
        if (img < B) {
            float lo[10];
            float mx = -1e30f;
#pragma unroll
            for (int o = 0; o < 10; ++o) { lo[o] = red[tid][o]; mx = fmaxf(mx, lo[o]); }
            float se = 0.f;
#pragma unroll
            for (int o = 0; o < 10; ++o) se += __expf(lo[o] - mx);
            const float lse = mx + __logf(se);
#pragma unroll
            for (int o = 0; o < 10; ++o) out[img * 10 + o] = lo[o] - lse;
        }
    }
}

extern "C" void kernel_launch(void* const* d_in, const int* in_sizes, int n_in,
                              void* d_out, int out_size, void* d_ws, size_t ws_size,
                              hipStream_t stream) {
    const float* x      = (const float*)d_in[0];  // [B,1,28,28]
    const float* params = (const float*)d_in[1];  // [3,4,3]
    const float* Wm     = (const float*)d_in[2];  // [10,784]
    const float* bv     = (const float*)d_in[3];  // [10]
    float* out          = (float*)d_out;          // [B,10]

    const int B = in_sizes[0] / 784;
    const int nblk = (B + IPB - 1) / IPB;
    quanv_fused4_kernel<<<nblk, BLK, 0, stream>>>(x, params, Wm, bv, out, B);
}